// Round 4
// baseline (351.019 us; speedup 1.0000x reference)
//
#include <hip/hip_runtime.h>
#include <hip/hip_bf16.h>
#include <math.h>

#define B_ 4
#define T_ 2048
#define D_ 128
#define H_ 8
#define BT_ (B_*T_)          // 8192
#define HD_ (H_*D_)          // 1024

typedef __attribute__((ext_vector_type(8))) short bf16x8;
typedef __attribute__((ext_vector_type(4))) float f32x4;

__device__ __forceinline__ short f2bf(float f) {
  union { float f; unsigned u; } v; v.f = f;
  return (short)((v.u + 0x8000u) >> 16);
}

#if __has_builtin(__builtin_amdgcn_exp2f)
#define EXP2F(x) __builtin_amdgcn_exp2f(x)
#else
#define EXP2F(x) exp2f(x)
#endif

#define QSCALE 0.12752040242046492f   // k^-0.5 * log2(e), folded into Q
#define VSCALE 0.29730177875068026f   // k^-0.25, folded into V

// ---------------------------------------------------------------------------
// Kernel 0: prep. blocks 0..23: transpose+convert Wq/Wk/Wv (128x1024 f32)
// into WT[wsel][n][k] bf16 (contiguous-k rows for pure-b128 GEMM staging).
// blocks 24..55: convert x (1M f32) to bf16.
// ---------------------------------------------------------------------------
__global__ __launch_bounds__(256) void prep(
    const float* __restrict__ x, const float* __restrict__ Wq,
    const float* __restrict__ Wk, const float* __restrict__ Wv,
    short* __restrict__ xbf, short* __restrict__ WT)
{
  __shared__ __align__(16) short Tt[128*128];
  const int tid = threadIdx.x;
  const int id = blockIdx.x;
  if (id < 24) {
    const int wsel = id >> 3, nt = id & 7;
    const float* W = (wsel == 0) ? Wq : (wsel == 1) ? Wk : Wv;
    #pragma unroll 4
    for (int i = tid; i < 4096; i += 256) {
      int k = i >> 5, n4 = (i & 31) << 2;
      float4 v = *(const float4*)&W[(size_t)k * HD_ + nt*128 + n4];
      float vv[4] = {v.x, v.y, v.z, v.w};
      #pragma unroll
      for (int j = 0; j < 4; j++) {
        int n = n4 + j;
        Tt[n*128 + (((k >> 3) ^ (n & 15)) << 3) + (k & 7)] = f2bf(vv[j]);
      }
    }
    __syncthreads();
    #pragma unroll 2
    for (int i = tid; i < 2048; i += 256) {
      int n = i >> 4, c = i & 15;
      *(bf16x8*)&WT[((size_t)wsel*1024 + nt*128 + n)*128 + (c << 3)] =
          *(bf16x8*)&Tt[n*128 + ((c ^ (n & 15)) << 3)];
    }
  } else {
    const int xb = id - 24;                       // 32 blocks
    const float4* xs = (const float4*)x + (size_t)xb * 8192;
    short4* xd = (short4*)xbf + (size_t)xb * 8192;
    #pragma unroll 8
    for (int i = tid; i < 8192; i += 256) {
      float4 v = xs[i];
      short4 p; p.x = f2bf(v.x); p.y = f2bf(v.y); p.z = f2bf(v.z); p.w = f2bf(v.w);
      xd[i] = p;
    }
  }
}

// ---------------------------------------------------------------------------
// Kernel 1: QKV as ONE GEMM: xbf(8192x128) @ [Wq|Wk|Wv]^T via WT.
// grid (64 m, 24 n) = 1536 blocks; pure b128 staging both operands.
// Q scaled by QSCALE; V scaled by VSCALE and stored transposed (B,H,128,T).
// ---------------------------------------------------------------------------
__global__ __launch_bounds__(256) void qkv_proj(
    const short* __restrict__ xbf, const short* __restrict__ WT,
    short* __restrict__ Qw, short* __restrict__ Kw, short* __restrict__ Vw)
{
  __shared__ __align__(16) short As[128*128];
  __shared__ __align__(16) short Bs[128*128];
  const int tid = threadIdx.x;
  const int m0 = blockIdx.x * 128;
  const int ng0 = blockIdx.y * 128;               // global n in [0,3072)

  #pragma unroll 4
  for (int i = tid; i < 2048; i += 256) {
    int row = i >> 4, c = i & 15;
    *(bf16x8*)&As[row*128 + ((c ^ (row & 15)) << 3)] =
        *(const bf16x8*)(xbf + (size_t)(m0 + row)*128 + (c << 3));
  }
  #pragma unroll 4
  for (int i = tid; i < 2048; i += 256) {
    int n = i >> 4, c = i & 15;
    *(bf16x8*)&Bs[n*128 + ((c ^ (n & 15)) << 3)] =
        *(const bf16x8*)(WT + (size_t)(ng0 + n)*128 + (c << 3));
  }
  __syncthreads();

  const int w = tid >> 6, lane = tid & 63, quad = lane >> 4, l16 = lane & 15;
  const int wm = (w & 1) * 64, wn = (w >> 1) * 64;

  f32x4 acc[4][4];
  #pragma unroll
  for (int a = 0; a < 4; a++)
    #pragma unroll
    for (int b = 0; b < 4; b++) acc[a][b] = (f32x4){0.f, 0.f, 0.f, 0.f};

  #pragma unroll
  for (int kk = 0; kk < 4; kk++) {
    const int swz = ((kk*4 + quad) ^ l16) << 3;
    bf16x8 af[4], bfv[4];
    #pragma unroll
    for (int mi = 0; mi < 4; mi++) af[mi]  = *(bf16x8*)&As[(wm + mi*16 + l16)*128 + swz];
    #pragma unroll
    for (int ni = 0; ni < 4; ni++) bfv[ni] = *(bf16x8*)&Bs[(wn + ni*16 + l16)*128 + swz];
    #pragma unroll
    for (int mi = 0; mi < 4; mi++)
      #pragma unroll
      for (int ni = 0; ni < 4; ni++)
        acc[mi][ni] = __builtin_amdgcn_mfma_f32_16x16x32_bf16(af[mi], bfv[ni], acc[mi][ni], 0, 0, 0);
  }

  const int wsel = (int)blockIdx.y >> 3;
  const int n0 = ((int)blockIdx.y & 7) * 128;
  const float oscale = (wsel == 0) ? QSCALE : 1.0f;
  #pragma unroll
  for (int mi = 0; mi < 4; mi++) {
    #pragma unroll
    for (int ni = 0; ni < 4; ni++) {
      const int mrow0 = m0 + wm + mi*16 + quad*4;
      const int ncol  = n0 + wn + ni*16 + l16;
      const int h = ncol >> 7, d = ncol & 127;
      const int b = mrow0 >> 11;
      if (wsel == 2) {
        const int t0 = mrow0 & 2047;
        short4 p;
        p.x = f2bf(acc[mi][ni][0] * VSCALE);
        p.y = f2bf(acc[mi][ni][1] * VSCALE);
        p.z = f2bf(acc[mi][ni][2] * VSCALE);
        p.w = f2bf(acc[mi][ni][3] * VSCALE);
        *(short4*)&Vw[((size_t)(b*H_ + h)*D_ + d)*T_ + t0] = p;
      } else {
        short* dst = (wsel == 0) ? Qw : Kw;
        #pragma unroll
        for (int r = 0; r < 4; r++) {
          const int t = (mrow0 + r) & 2047;
          dst[((size_t)(b*H_ + h)*T_ + t)*D_ + d] = f2bf(acc[mi][ni][r] * oscale);
        }
      }
    }
  }
}

// ---------------------------------------------------------------------------
// Kernel 2: causal flash attention, UNPAIRED: one 64-row q-tile per block,
// grid 1024 (4 blocks/CU, 16 waves/CU). Per-XCD slot mapping balances the
// four likely-co-resident blocks to exactly 66 iterations per CU:
// slots get qi = {q, 15-q, 16+q, 31-q}.
// ---------------------------------------------------------------------------
__global__ __launch_bounds__(256, 4) void attn_kernel(
    const short* __restrict__ Qw, const short* __restrict__ Kw,
    const short* __restrict__ Vw, short* __restrict__ attnw)
{
  __shared__ __align__(16) short Ks[64*128];
  __shared__ __align__(16) short Vs[128*64];
  __shared__ __align__(16) short Ps[4*16*64];

  const int tid = threadIdx.x;
  const int id = (int)blockIdx.x;                 // 1024 blocks
  const int c  = id & 7;                          // XCD
  const int j  = id >> 3;                         // 0..127 within XCD
  const int bh = c | ((j & 3) << 3);              // 4 bh per XCD
  const int slot = j >> 5, q = (j >> 2) & 7;
  const int qi = (slot == 0) ? q : (slot == 1) ? 15 - q
               : (slot == 2) ? 16 + q : 31 - q;
  const int b = bh >> 3, h = bh & 7;
  const int w = tid >> 6, lane = tid & 63, quad = lane >> 4, l16 = lane & 15;
  const int rowQ = qi*64 + w*16;

  const short* Qp = Qw + (size_t)bh * T_ * D_;
  const short* Kp = Kw + (size_t)bh * T_ * D_;
  const short* Vp = Vw + (size_t)bh * D_ * T_;

  bf16x8 qa[4];
  #pragma unroll
  for (int kk = 0; kk < 4; kk++)
    qa[kk] = *(const bf16x8*)(Qp + (size_t)(rowQ + l16)*D_ + kk*32 + quad*8);

  f32x4 o[8];
  #pragma unroll
  for (int e = 0; e < 8; e++) o[e] = (f32x4){0,0,0,0};
  float l[4] = {0,0,0,0};

  short* Pw = &Ps[w*16*64];
  const int nIter = qi + 1;

  bf16x8 kreg[4], vreg[4];
  #pragma unroll
  for (int jj = 0; jj < 4; jj++) {
    int i = tid + 256*jj;
    kreg[jj] = *(const bf16x8*)(Kp + (size_t)(i >> 4)*D_ + ((i & 15) << 3));
    vreg[jj] = *(const bf16x8*)(Vp + (size_t)(i >> 3)*T_ + ((i & 7) << 3));
  }

  for (int it = 0; it < nIter; ++it) {
    if (it) __syncthreads();
    #pragma unroll
    for (int jj = 0; jj < 4; jj++) {
      int i = tid + 256*jj;
      int row = i >> 4, cc = i & 15;
      *(bf16x8*)&Ks[row*128 + ((cc ^ (row & 15)) << 3)] = kreg[jj];
      int e = i >> 3, c2 = i & 7;
      *(bf16x8*)&Vs[e*64 + ((c2 ^ (e & 7)) << 3)] = vreg[jj];
    }
    __syncthreads();
    if (it + 1 < nIter) {
      const int s1 = (it + 1) * 64;
      #pragma unroll
      for (int jj = 0; jj < 4; jj++) {
        int i = tid + 256*jj;
        kreg[jj] = *(const bf16x8*)(Kp + (size_t)(s1 + (i >> 4))*D_ + ((i & 15) << 3));
        vreg[jj] = *(const bf16x8*)(Vp + (size_t)(i >> 3)*T_ + s1 + ((i & 7) << 3));
      }
    }

    f32x4 s[4];
    #pragma unroll
    for (int nj = 0; nj < 4; nj++) s[nj] = (f32x4){0,0,0,0};
    #pragma unroll
    for (int kk = 0; kk < 4; kk++) {
      const int swz = ((kk*4 + quad) ^ l16) << 3;
      #pragma unroll
      for (int nj = 0; nj < 4; nj++) {
        bf16x8 kb = *(bf16x8*)&Ks[(nj*16 + l16)*128 + swz];
        s[nj] = __builtin_amdgcn_mfma_f32_16x16x32_bf16(qa[kk], kb, s[nj], 0, 0, 0);
      }
    }

    // softmax (fixed-max exp2 domain), P -> per-wave LDS
    if (it < qi) {                                 // unmasked tile
      #pragma unroll
      for (int nj = 0; nj < 4; nj++) {
        #pragma unroll
        for (int r = 0; r < 4; r++) {
          float p = EXP2F(s[nj][r]);
          l[r] += p;
          const int row = quad*4 + r, col = nj*16 + l16;
          Pw[row*64 + (((col >> 3) ^ (row & 7)) << 3) + (col & 7)] = f2bf(p);
        }
      }
    } else {                                       // diagonal tile: mask
      const int s0 = it * 64;
      #pragma unroll
      for (int nj = 0; nj < 4; nj++) {
        const int key = s0 + nj*16 + l16;
        #pragma unroll
        for (int r = 0; r < 4; r++) {
          float p = (key > rowQ + quad*4 + r) ? 0.f : EXP2F(s[nj][r]);
          l[r] += p;
          const int row = quad*4 + r, col = nj*16 + l16;
          Pw[row*64 + (((col >> 3) ^ (row & 7)) << 3) + (col & 7)] = f2bf(p);
        }
      }
    }

    #pragma unroll
    for (int kk2 = 0; kk2 < 2; kk2++) {
      const int swz = ((kk2*4 + quad) ^ (l16 & 7)) << 3;
      bf16x8 pa = *(bf16x8*)&Pw[l16*64 + swz];
      #pragma unroll
      for (int e = 0; e < 8; e++) {
        bf16x8 vb = *(const bf16x8*)&Vs[(e*16 + l16)*64 + swz];
        o[e] = __builtin_amdgcn_mfma_f32_16x16x32_bf16(pa, vb, o[e], 0, 0, 0);
      }
    }
    __syncthreads();
  }

  #pragma unroll
  for (int r = 0; r < 4; r++) {
    float t = l[r];
    t += __shfl_xor(t, 1); t += __shfl_xor(t, 2);
    t += __shfl_xor(t, 4); t += __shfl_xor(t, 8);
    l[r] = 1.0f / t;
  }
  #pragma unroll
  for (int e = 0; e < 8; e++) {
    #pragma unroll
    for (int r = 0; r < 4; r++) {
      const int t = rowQ + quad*4 + r;
      attnw[((size_t)(b*T_ + t))*HD_ + h*D_ + e*16 + l16] = f2bf(o[e][r] * l[r]);
    }
  }
}

// ---------------------------------------------------------------------------
// Kernel 3: Wu(1024x128 f32) -> WuT(128x1024 bf16). grid 8. Into dead Kw.
// ---------------------------------------------------------------------------
__global__ __launch_bounds__(256) void wu_transpose(
    const float* __restrict__ Wu, short* __restrict__ WuT)
{
  __shared__ __align__(16) short Tt[128*128];
  const int tid = threadIdx.x;
  const int k0 = blockIdx.x * 128;
  #pragma unroll 4
  for (int i = tid; i < 4096; i += 256) {
    int k = i >> 5, n4 = (i & 31) << 2;
    float4 v = *(const float4*)&Wu[(size_t)(k0 + k) * D_ + n4];
    float vv[4] = {v.x, v.y, v.z, v.w};
    #pragma unroll
    for (int jj = 0; jj < 4; jj++) {
      int n = n4 + jj;
      Tt[n*128 + (((k >> 3) ^ (n & 15)) << 3) + (k & 7)] = f2bf(vv[jj]);
    }
  }
  __syncthreads();
  #pragma unroll 2
  for (int i = tid; i < 2048; i += 256) {
    int n = i >> 4, cc = i & 15;
    *(bf16x8*)&WuT[(size_t)n * HD_ + k0 + (cc << 3)] =
        *(bf16x8*)&Tt[n*128 + ((cc ^ (n & 15)) << 3)];
  }
}

// ---------------------------------------------------------------------------
// Kernel 4: out_proj split-K=2. grid (256 m-tiles of 32, 2 k-halves).
// Wave w: row-group (w&1)*16, e-half (w>>1). fp32 partials into pws.
// ---------------------------------------------------------------------------
__global__ __launch_bounds__(256) void out_proj(
    const short* __restrict__ attnw, const short* __restrict__ WuT,
    float* __restrict__ pws)
{
  __shared__ __align__(16) short As2[32*128];
  __shared__ __align__(16) short Bs2[128*128];
  const int tid = threadIdx.x;
  const int m0 = blockIdx.x * 32;
  const int kh = blockIdx.y;
  const int w = tid >> 6, lane = tid & 63, quad = lane >> 4, l16 = lane & 15;
  const int rw = (w & 1) * 16, eh = (w >> 1) * 4;

  f32x4 o[4];
  #pragma unroll
  for (int e = 0; e < 4; e++) o[e] = (f32x4){0.f, 0.f, 0.f, 0.f};

  for (int kc = 0; kc < 4; kc++) {
    const int kbase = kh*512 + kc*128;
    if (kc) __syncthreads();
    #pragma unroll 2
    for (int i = tid; i < 512; i += 256) {
      int row = i >> 4, cc = i & 15;
      *(bf16x8*)&As2[row*128 + ((cc ^ (row & 15)) << 3)] =
          *(const bf16x8*)(attnw + (size_t)(m0 + row)*HD_ + kbase + (cc << 3));
    }
    #pragma unroll 8
    for (int i = tid; i < 2048; i += 256) {
      int n = i >> 4, cc = i & 15;
      *(bf16x8*)&Bs2[n*128 + ((cc ^ (n & 15)) << 3)] =
          *(const bf16x8*)(WuT + (size_t)n*HD_ + kbase + (cc << 3));
    }
    __syncthreads();
    #pragma unroll
    for (int kk = 0; kk < 4; kk++) {
      const int swz = ((kk*4 + quad) ^ l16) << 3;
      bf16x8 a = *(bf16x8*)&As2[(rw + l16)*128 + swz];
      #pragma unroll
      for (int e = 0; e < 4; e++) {
        bf16x8 bfr = *(bf16x8*)&Bs2[((eh + e)*16 + l16)*128 + swz];
        o[e] = __builtin_amdgcn_mfma_f32_16x16x32_bf16(a, bfr, o[e], 0, 0, 0);
      }
    }
  }

  float* dst = pws + (size_t)kh * BT_ * D_;
  #pragma unroll
  for (int e = 0; e < 4; e++) {
    const int n = (eh + e)*16 + l16;
    #pragma unroll
    for (int r = 0; r < 4; r++) {
      const int m = m0 + rw + quad*4 + r;
      dst[(size_t)m*D_ + n] = o[e][r];
    }
  }
}

// ---------------------------------------------------------------------------
// Kernel 5: out = p0 + p1 + bias. 1M f32 via float4.
// ---------------------------------------------------------------------------
__global__ __launch_bounds__(256) void reduce_bias(
    const float* __restrict__ pws, const float* __restrict__ bu,
    float* __restrict__ out)
{
  const int base = ((int)blockIdx.x * 256 + (int)threadIdx.x) * 4;
  const float4* p0 = (const float4*)pws;
  const float4* p1 = (const float4*)(pws + (size_t)BT_ * D_);
  const float4* b4 = (const float4*)bu;
  float4* o4 = (float4*)out;
  #pragma unroll
  for (int jj = 0; jj < 4; jj++) {
    int i = base + jj;
    float4 a = p0[i], b = p1[i], c = b4[i & 31];
    float4 r; r.x = a.x + b.x + c.x; r.y = a.y + b.y + c.y;
    r.z = a.z + b.z + c.z; r.w = a.w + b.w + c.w;
    o4[i] = r;
  }
}

extern "C" void kernel_launch(void* const* d_in, const int* in_sizes, int n_in,
                              void* d_out, int out_size, void* d_ws, size_t ws_size,
                              hipStream_t stream) {
  (void)in_sizes; (void)n_in; (void)out_size; (void)ws_size;
  const float* x  = (const float*)d_in[0];
  const float* Wq = (const float*)d_in[1];
  const float* Wk = (const float*)d_in[2];
  const float* Wv = (const float*)d_in[3];
  const float* Wu = (const float*)d_in[4];
  const float* bu = (const float*)d_in[5];
  float* out = (float*)d_out;

  const size_t headElems = (size_t)B_ * H_ * T_ * D_;   // 8,388,608
  short* Qw    = (short*)d_ws;
  short* Kw    = Qw + headElems;
  short* Vw    = Kw + headElems;
  short* attnw = Vw + headElems;                        // 16 MB region
  // prep outputs live in the (not-yet-written) attnw region:
  short* xbf = attnw;                                   // 2 MB
  short* WT  = attnw + (size_t)BT_ * D_;                // 0.75 MB
  short* WuT = Kw;                                      // Kw dead after attn
  float* pws = (float*)Qw;                              // Qw dead after attn (8 MB)

  prep<<<dim3(56), 256, 0, stream>>>(x, Wq, Wk, Wv, xbf, WT);
  qkv_proj<<<dim3(64, 24), 256, 0, stream>>>(xbf, WT, Qw, Kw, Vw);
  attn_kernel<<<dim3(1024), 256, 0, stream>>>(Qw, Kw, Vw, attnw);
  wu_transpose<<<dim3(8), 256, 0, stream>>>(Wu, WuT);
  out_proj<<<dim3(256, 2), 256, 0, stream>>>(attnw, WuT, pws);
  reduce_bias<<<dim3(256), 256, 0, stream>>>(pws, bu, out);
}

// Round 5
// 166.931 us; speedup vs baseline: 2.1028x; 2.1028x over previous
//
#include <hip/hip_runtime.h>
#include <hip/hip_bf16.h>
#include <math.h>

#define B_ 4
#define T_ 2048
#define D_ 128
#define H_ 8
#define BT_ (B_*T_)          // 8192
#define HD_ (H_*D_)          // 1024

typedef __attribute__((ext_vector_type(8))) short bf16x8;
typedef __attribute__((ext_vector_type(4))) float f32x4;

__device__ __forceinline__ short f2bf(float f) {
  union { float f; unsigned u; } v; v.f = f;
  return (short)((v.u + 0x8000u) >> 16);
}

#if __has_builtin(__builtin_amdgcn_exp2f)
#define EXP2F(x) __builtin_amdgcn_exp2f(x)
#else
#define EXP2F(x) exp2f(x)
#endif

#define QSCALE 0.12752040242046492f   // k^-0.5 * log2(e), folded into Q
#define VSCALE 0.29730177875068026f   // k^-0.25, folded into V

// async global->LDS DMA, 16B per lane; LDS dest = wave-uniform base + lane*16
__device__ __forceinline__ void gld16(const short* g, short* l) {
  __builtin_amdgcn_global_load_lds(
      (const __attribute__((address_space(1))) void*)g,
      (__attribute__((address_space(3))) void*)l, 16, 0, 0);
}

// ---------------------------------------------------------------------------
// Kernel 0: prep. blocks 0..23: transpose+convert Wq/Wk/Wv (128x1024 f32)
// into WT[wsel][n][k] bf16. blocks 24..151: x (1M f32) -> bf16.
// ---------------------------------------------------------------------------
__global__ __launch_bounds__(256) void prep(
    const float* __restrict__ x, const float* __restrict__ Wq,
    const float* __restrict__ Wk, const float* __restrict__ Wv,
    short* __restrict__ xbf, short* __restrict__ WT)
{
  __shared__ __align__(16) short Tt[128*128];
  const int tid = threadIdx.x;
  const int id = blockIdx.x;
  if (id < 24) {
    const int wsel = id >> 3, nt = id & 7;
    const float* W = (wsel == 0) ? Wq : (wsel == 1) ? Wk : Wv;
    #pragma unroll 4
    for (int i = tid; i < 4096; i += 256) {
      int k = i >> 5, n4 = (i & 31) << 2;
      float4 v = *(const float4*)&W[(size_t)k * HD_ + nt*128 + n4];
      float vv[4] = {v.x, v.y, v.z, v.w};
      #pragma unroll
      for (int j = 0; j < 4; j++) {
        int n = n4 + j;
        Tt[n*128 + (((k >> 3) ^ (n & 15)) << 3) + (k & 7)] = f2bf(vv[j]);
      }
    }
    __syncthreads();
    #pragma unroll 2
    for (int i = tid; i < 2048; i += 256) {
      int n = i >> 4, c = i & 15;
      *(bf16x8*)&WT[((size_t)wsel*1024 + nt*128 + n)*128 + (c << 3)] =
          *(bf16x8*)&Tt[n*128 + ((c ^ (n & 15)) << 3)];
    }
  } else {
    const int xb = id - 24;                       // 128 blocks
    const float4* xs = (const float4*)x + (size_t)xb * 2048;
    short4* xd = (short4*)xbf + (size_t)xb * 2048;
    #pragma unroll 8
    for (int i = tid; i < 2048; i += 256) {
      float4 v = xs[i];
      short4 p; p.x = f2bf(v.x); p.y = f2bf(v.y); p.z = f2bf(v.z); p.w = f2bf(v.w);
      xd[i] = p;
    }
  }
}

// ---------------------------------------------------------------------------
// Kernel 1: QKV as ONE GEMM: xbf(8192x128) @ [Wq|Wk|Wv]^T via WT.
// grid (64 m, 24 n); pure b128 staging. Q scaled by QSCALE, row-major.
// K and V written PRE-SWIZZLED in 16KB tiles so attn can stage them with
// global_load_lds (contiguous DMA == swizzled LDS image):
//  K tile (64 t x 128 d): chunk pos = tl*16 + ((d>>3) ^ (tl&15)), intra d&7
//  V tile (128 d x 64 t): chunk pos = d*8 + ((tl>>3) ^ (d&7)), intra tl&7
// ---------------------------------------------------------------------------
__global__ __launch_bounds__(256) void qkv_proj(
    const short* __restrict__ xbf, const short* __restrict__ WT,
    short* __restrict__ Qw, short* __restrict__ Kw, short* __restrict__ Vw)
{
  __shared__ __align__(16) short As[128*128];
  __shared__ __align__(16) short Bs[128*128];
  const int tid = threadIdx.x;
  const int m0 = blockIdx.x * 128;
  const int ng0 = blockIdx.y * 128;

  #pragma unroll 4
  for (int i = tid; i < 2048; i += 256) {
    int row = i >> 4, c = i & 15;
    *(bf16x8*)&As[row*128 + ((c ^ (row & 15)) << 3)] =
        *(const bf16x8*)(xbf + (size_t)(m0 + row)*128 + (c << 3));
  }
  #pragma unroll 4
  for (int i = tid; i < 2048; i += 256) {
    int n = i >> 4, c = i & 15;
    *(bf16x8*)&Bs[n*128 + ((c ^ (n & 15)) << 3)] =
        *(const bf16x8*)(WT + (size_t)(ng0 + n)*128 + (c << 3));
  }
  __syncthreads();

  const int w = tid >> 6, lane = tid & 63, quad = lane >> 4, l16 = lane & 15;
  const int wm = (w & 1) * 64, wn = (w >> 1) * 64;

  f32x4 acc[4][4];
  #pragma unroll
  for (int a = 0; a < 4; a++)
    #pragma unroll
    for (int b = 0; b < 4; b++) acc[a][b] = (f32x4){0.f, 0.f, 0.f, 0.f};

  #pragma unroll
  for (int kk = 0; kk < 4; kk++) {
    const int swz = ((kk*4 + quad) ^ l16) << 3;
    bf16x8 af[4], bfv[4];
    #pragma unroll
    for (int mi = 0; mi < 4; mi++) af[mi]  = *(bf16x8*)&As[(wm + mi*16 + l16)*128 + swz];
    #pragma unroll
    for (int ni = 0; ni < 4; ni++) bfv[ni] = *(bf16x8*)&Bs[(wn + ni*16 + l16)*128 + swz];
    #pragma unroll
    for (int mi = 0; mi < 4; mi++)
      #pragma unroll
      for (int ni = 0; ni < 4; ni++)
        acc[mi][ni] = __builtin_amdgcn_mfma_f32_16x16x32_bf16(af[mi], bfv[ni], acc[mi][ni], 0, 0, 0);
  }

  const int wsel = (int)blockIdx.y >> 3;
  const int n0 = ((int)blockIdx.y & 7) * 128;
  #pragma unroll
  for (int mi = 0; mi < 4; mi++) {
    #pragma unroll
    for (int ni = 0; ni < 4; ni++) {
      const int mrow0 = m0 + wm + mi*16 + quad*4;
      const int ncol  = n0 + wn + ni*16 + l16;
      const int h = ncol >> 7, d = ncol & 127;
      const int b = mrow0 >> 11;
      const int bhh = b*H_ + h;
      if (wsel == 2) {
        const int t0 = mrow0 & 2047;
        const int tile = t0 >> 6, tl0 = t0 & 63;
        const size_t base = ((size_t)bhh*32 + tile) * 8192;
        short4 p;
        p.x = f2bf(acc[mi][ni][0] * VSCALE);
        p.y = f2bf(acc[mi][ni][1] * VSCALE);
        p.z = f2bf(acc[mi][ni][2] * VSCALE);
        p.w = f2bf(acc[mi][ni][3] * VSCALE);
        *(short4*)&Vw[base + (((d << 3) | ((tl0 >> 3) ^ (d & 7))) << 3) + (tl0 & 7)] = p;
      } else if (wsel == 1) {
        #pragma unroll
        for (int r = 0; r < 4; r++) {
          const int t = (mrow0 + r) & 2047;
          const int tile = t >> 6, tl = t & 63;
          const size_t base = ((size_t)bhh*32 + tile) * 8192;
          Kw[base + ((((tl << 4) | ((d >> 3) ^ (tl & 15)))) << 3) + (d & 7)] =
              f2bf(acc[mi][ni][r]);
        }
      } else {
        #pragma unroll
        for (int r = 0; r < 4; r++) {
          const int t = (mrow0 + r) & 2047;
          Qw[((size_t)bhh*T_ + t)*D_ + d] = f2bf(acc[mi][ni][r] * QSCALE);
        }
      }
    }
  }
}

// ---------------------------------------------------------------------------
// Kernel 2: causal flash attention. One 64-row q-tile per block, grid 1024
// (4 blocks/CU, 16 waves/CU, LDS 4x40KB=160KB). Staging via global_load_lds
// from pre-swizzled K/V tiles (no staging VGPRs -> ~90 regs, no spill).
// qi from slot=(j&3)^((j>>5)&3): any co-resident group of 4 (consecutive j
// OR j+{0,32,64,96}) sums to exactly 66 iterations.
// ---------------------------------------------------------------------------
__global__ __launch_bounds__(256, 4) void attn_kernel(
    const short* __restrict__ Qw, const short* __restrict__ Kw,
    const short* __restrict__ Vw, short* __restrict__ attnw)
{
  __shared__ __align__(16) short Ks[64*128];
  __shared__ __align__(16) short Vs[128*64];
  __shared__ __align__(16) short Ps[4*16*64];

  const int tid = threadIdx.x;
  const int id = (int)blockIdx.x;                 // 1024 blocks
  const int xcd = id & 7;
  const int j   = id >> 3;                        // 0..127 within XCD
  const int u   = j & 3;
  const int q   = (j >> 2) & 7;
  const int vv  = (j >> 5) & 3;
  const int slot = u ^ vv;
  const int qi = (slot == 0) ? q : (slot == 1) ? 15 - q
               : (slot == 2) ? 16 + q : 31 - q;
  const int bh = xcd | (u << 3);
  const int b = bh >> 3, h = bh & 7;
  const int w = tid >> 6, lane = tid & 63, quad = lane >> 4, l16 = lane & 15;
  const int rowQ = qi*64 + w*16;

  const short* Qp = Qw + (size_t)bh * T_ * D_;
  const short* Kp = Kw + (size_t)bh * T_ * D_;    // 32 tiles x 8192 shorts
  const short* Vp = Vw + (size_t)bh * D_ * T_;

  bf16x8 qa[4];
  #pragma unroll
  for (int kk = 0; kk < 4; kk++)
    qa[kk] = *(const bf16x8*)(Qp + (size_t)(rowQ + l16)*D_ + kk*32 + quad*8);

  f32x4 o[8];
  #pragma unroll
  for (int e = 0; e < 8; e++) o[e] = (f32x4){0,0,0,0};
  float l[4] = {0,0,0,0};

  short* Pw = &Ps[w*16*64];
  const int nIter = qi + 1;

  for (int it = 0; it < nIter; ++it) {
    if (it) __syncthreads();                      // consumers done w/ prev tile
    {
      const short* kt = Kp + ((size_t)it << 13);
      const short* vt = Vp + ((size_t)it << 13);
      const int wo = w*2048 + lane*8;
      #pragma unroll
      for (int cc = 0; cc < 4; cc++) {
        gld16(kt + wo + cc*512, &Ks[w*2048 + cc*512]);
        gld16(vt + wo + cc*512, &Vs[w*2048 + cc*512]);
      }
    }
    __syncthreads();                              // vmcnt drained before barrier

    f32x4 s[4];
    #pragma unroll
    for (int nj = 0; nj < 4; nj++) s[nj] = (f32x4){0,0,0,0};
    #pragma unroll
    for (int kk = 0; kk < 4; kk++) {
      const int swz = ((kk*4 + quad) ^ l16) << 3;
      #pragma unroll
      for (int nj = 0; nj < 4; nj++) {
        bf16x8 kb = *(bf16x8*)&Ks[(nj*16 + l16)*128 + swz];
        s[nj] = __builtin_amdgcn_mfma_f32_16x16x32_bf16(qa[kk], kb, s[nj], 0, 0, 0);
      }
    }

    if (it < qi) {                                // unmasked tile
      #pragma unroll
      for (int nj = 0; nj < 4; nj++) {
        #pragma unroll
        for (int r = 0; r < 4; r++) {
          float p = EXP2F(s[nj][r]);
          l[r] += p;
          const int row = quad*4 + r, col = nj*16 + l16;
          Pw[row*64 + (((col >> 3) ^ (row & 7)) << 3) + (col & 7)] = f2bf(p);
        }
      }
    } else {                                      // diagonal tile: mask
      const int s0 = it * 64;
      #pragma unroll
      for (int nj = 0; nj < 4; nj++) {
        const int key = s0 + nj*16 + l16;
        #pragma unroll
        for (int r = 0; r < 4; r++) {
          float p = (key > rowQ + quad*4 + r) ? 0.f : EXP2F(s[nj][r]);
          l[r] += p;
          const int row = quad*4 + r, col = nj*16 + l16;
          Pw[row*64 + (((col >> 3) ^ (row & 7)) << 3) + (col & 7)] = f2bf(p);
        }
      }
    }

    #pragma unroll
    for (int kk2 = 0; kk2 < 2; kk2++) {
      const int swz = ((kk2*4 + quad) ^ (l16 & 7)) << 3;
      bf16x8 pa = *(bf16x8*)&Pw[l16*64 + swz];
      #pragma unroll
      for (int e = 0; e < 8; e++) {
        bf16x8 vb = *(const bf16x8*)&Vs[(e*16 + l16)*64 + swz];
        o[e] = __builtin_amdgcn_mfma_f32_16x16x32_bf16(pa, vb, o[e], 0, 0, 0);
      }
    }
    __syncthreads();
  }

  #pragma unroll
  for (int r = 0; r < 4; r++) {
    float t = l[r];
    t += __shfl_xor(t, 1); t += __shfl_xor(t, 2);
    t += __shfl_xor(t, 4); t += __shfl_xor(t, 8);
    l[r] = 1.0f / t;
  }
  #pragma unroll
  for (int e = 0; e < 8; e++) {
    #pragma unroll
    for (int r = 0; r < 4; r++) {
      const int t = rowQ + quad*4 + r;
      attnw[((size_t)(b*T_ + t))*HD_ + h*D_ + e*16 + l16] = f2bf(o[e][r] * l[r]);
    }
  }
}

// ---------------------------------------------------------------------------
// Kernel 3: Wu(1024x128 f32) -> WuT(128x1024 bf16). grid 8. Into dead Kw.
// ---------------------------------------------------------------------------
__global__ __launch_bounds__(256) void wu_transpose(
    const float* __restrict__ Wu, short* __restrict__ WuT)
{
  __shared__ __align__(16) short Tt[128*128];
  const int tid = threadIdx.x;
  const int k0 = blockIdx.x * 128;
  #pragma unroll 4
  for (int i = tid; i < 4096; i += 256) {
    int k = i >> 5, n4 = (i & 31) << 2;
    float4 v = *(const float4*)&Wu[(size_t)(k0 + k) * D_ + n4];
    float vv[4] = {v.x, v.y, v.z, v.w};
    #pragma unroll
    for (int jj = 0; jj < 4; jj++) {
      int n = n4 + jj;
      Tt[n*128 + (((k >> 3) ^ (n & 15)) << 3) + (k & 7)] = f2bf(vv[jj]);
    }
  }
  __syncthreads();
  #pragma unroll 2
  for (int i = tid; i < 2048; i += 256) {
    int n = i >> 4, cc = i & 15;
    *(bf16x8*)&WuT[(size_t)n * HD_ + k0 + (cc << 3)] =
        *(bf16x8*)&Tt[n*128 + ((cc ^ (n & 15)) << 3)];
  }
}

// ---------------------------------------------------------------------------
// Kernel 4: out_proj split-K=2. grid (256 m-tiles of 32, 2 k-halves).
// ---------------------------------------------------------------------------
__global__ __launch_bounds__(256) void out_proj(
    const short* __restrict__ attnw, const short* __restrict__ WuT,
    float* __restrict__ pws)
{
  __shared__ __align__(16) short As2[32*128];
  __shared__ __align__(16) short Bs2[128*128];
  const int tid = threadIdx.x;
  const int m0 = blockIdx.x * 32;
  const int kh = blockIdx.y;
  const int w = tid >> 6, lane = tid & 63, quad = lane >> 4, l16 = lane & 15;
  const int rw = (w & 1) * 16, eh = (w >> 1) * 4;

  f32x4 o[4];
  #pragma unroll
  for (int e = 0; e < 4; e++) o[e] = (f32x4){0.f, 0.f, 0.f, 0.f};

  for (int kc = 0; kc < 4; kc++) {
    const int kbase = kh*512 + kc*128;
    if (kc) __syncthreads();
    #pragma unroll 2
    for (int i = tid; i < 512; i += 256) {
      int row = i >> 4, cc = i & 15;
      *(bf16x8*)&As2[row*128 + ((cc ^ (row & 15)) << 3)] =
          *(const bf16x8*)(attnw + (size_t)(m0 + row)*HD_ + kbase + (cc << 3));
    }
    #pragma unroll 8
    for (int i = tid; i < 2048; i += 256) {
      int n = i >> 4, cc = i & 15;
      *(bf16x8*)&Bs2[n*128 + ((cc ^ (n & 15)) << 3)] =
          *(const bf16x8*)(WuT + (size_t)n*HD_ + kbase + (cc << 3));
    }
    __syncthreads();
    #pragma unroll
    for (int kk = 0; kk < 4; kk++) {
      const int swz = ((kk*4 + quad) ^ l16) << 3;
      bf16x8 a = *(bf16x8*)&As2[(rw + l16)*128 + swz];
      #pragma unroll
      for (int e = 0; e < 4; e++) {
        bf16x8 bfr = *(bf16x8*)&Bs2[((eh + e)*16 + l16)*128 + swz];
        o[e] = __builtin_amdgcn_mfma_f32_16x16x32_bf16(a, bfr, o[e], 0, 0, 0);
      }
    }
  }

  float* dst = pws + (size_t)kh * BT_ * D_;
  #pragma unroll
  for (int e = 0; e < 4; e++) {
    const int n = (eh + e)*16 + l16;
    #pragma unroll
    for (int r = 0; r < 4; r++) {
      const int m = m0 + rw + quad*4 + r;
      dst[(size_t)m*D_ + n] = o[e][r];
    }
  }
}

// ---------------------------------------------------------------------------
// Kernel 5: out = p0 + p1 + bias. 1M f32 via float4.
// ---------------------------------------------------------------------------
__global__ __launch_bounds__(256) void reduce_bias(
    const float* __restrict__ pws, const float* __restrict__ bu,
    float* __restrict__ out)
{
  const int base = ((int)blockIdx.x * 256 + (int)threadIdx.x) * 4;
  const float4* p0 = (const float4*)pws;
  const float4* p1 = (const float4*)(pws + (size_t)BT_ * D_);
  const float4* b4 = (const float4*)bu;
  float4* o4 = (float4*)out;
  #pragma unroll
  for (int jj = 0; jj < 4; jj++) {
    int i = base + jj;
    float4 a = p0[i], b = p1[i], c = b4[i & 31];
    float4 r; r.x = a.x + b.x + c.x; r.y = a.y + b.y + c.y;
    r.z = a.z + b.z + c.z; r.w = a.w + b.w + c.w;
    o4[i] = r;
  }
}

extern "C" void kernel_launch(void* const* d_in, const int* in_sizes, int n_in,
                              void* d_out, int out_size, void* d_ws, size_t ws_size,
                              hipStream_t stream) {
  (void)in_sizes; (void)n_in; (void)out_size; (void)ws_size;
  const float* x  = (const float*)d_in[0];
  const float* Wq = (const float*)d_in[1];
  const float* Wk = (const float*)d_in[2];
  const float* Wv = (const float*)d_in[3];
  const float* Wu = (const float*)d_in[4];
  const float* bu = (const float*)d_in[5];
  float* out = (float*)d_out;

  const size_t headElems = (size_t)B_ * H_ * T_ * D_;   // 8,388,608
  short* Qw    = (short*)d_ws;
  short* Kw    = Qw + headElems;
  short* Vw    = Kw + headElems;
  short* attnw = Vw + headElems;                        // 16 MB region
  short* xbf = attnw;                                   // prep outputs live in
  short* WT  = attnw + (size_t)BT_ * D_;                // not-yet-written attnw
  short* WuT = Kw;                                      // Kw dead after attn
  float* pws = (float*)Qw;                              // Qw dead after attn

  prep<<<dim3(152), 256, 0, stream>>>(x, Wq, Wk, Wv, xbf, WT);
  qkv_proj<<<dim3(64, 24), 256, 0, stream>>>(xbf, WT, Qw, Kw, Vw);
  attn_kernel<<<dim3(1024), 256, 0, stream>>>(Qw, Kw, Vw, attnw);
  wu_transpose<<<dim3(8), 256, 0, stream>>>(Wu, WuT);
  out_proj<<<dim3(256, 2), 256, 0, stream>>>(attnw, WuT, pws);
  reduce_bias<<<dim3(256), 256, 0, stream>>>(pws, bu, out);
}

// Round 6
// 160.270 us; speedup vs baseline: 2.1902x; 1.0416x over previous
//
#include <hip/hip_runtime.h>
#include <hip/hip_bf16.h>
#include <math.h>

#define B_ 4
#define T_ 2048
#define D_ 128
#define H_ 8
#define BT_ 8192
#define HD_ 1024

typedef __attribute__((ext_vector_type(8))) short bf16x8;
typedef __attribute__((ext_vector_type(4))) float f32x4;

__device__ __forceinline__ short f2bf(float f) {
  union { float f; unsigned u; } v; v.f = f;
  return (short)((v.u + 0x8000u) >> 16);
}

#if __has_builtin(__builtin_amdgcn_exp2f)
#define EXP2F(x) __builtin_amdgcn_exp2f(x)
#else
#define EXP2F(x) exp2f(x)
#endif

#define QSCALE 0.12752040242046492f   // k^-0.5 * log2(e), folded into Q
#define VSCALE 0.29730177875068026f   // k^-0.25, folded into V

// async global->LDS DMA, 16B/lane; LDS dest = wave-uniform base + lane*16
__device__ __forceinline__ void gld16(const short* g, short* l) {
  __builtin_amdgcn_global_load_lds(
      (const __attribute__((address_space(1))) void*)g,
      (__attribute__((address_space(3))) void*)l, 16, 0, 0);
}

// ---------------------------------------------------------------------------
// Kernel 0: prep. blocks 0..23: Wq/Wk/Wv (128x1024 f32) -> WT tile images
// (24 tiles of 128n x 128k bf16, swizzled: pos = n*16 + (c^(n&15)) chunks).
// blocks 24..87: x -> xbf tile images (64 tiles of 128m x 128k, same swizzle).
// Tile images are the exact LDS image qkv_proj wants -> staged via pure DMA.
// ---------------------------------------------------------------------------
__global__ __launch_bounds__(256) void prep(
    const float* __restrict__ x, const float* __restrict__ Wq,
    const float* __restrict__ Wk, const float* __restrict__ Wv,
    short* __restrict__ xbf, short* __restrict__ WT)
{
  __shared__ __align__(16) short Tt[128*128];
  const int tid = threadIdx.x;
  const int id = blockIdx.x;
  if (id < 24) {
    const int wsel = id >> 3, nt = id & 7;
    const float* W = (wsel == 0) ? Wq : (wsel == 1) ? Wk : Wv;
    #pragma unroll 4
    for (int i = tid; i < 4096; i += 256) {
      int k = i >> 5, n4 = (i & 31) << 2;
      float4 v = *(const float4*)&W[(size_t)k * HD_ + nt*128 + n4];
      float vv[4] = {v.x, v.y, v.z, v.w};
      #pragma unroll
      for (int j = 0; j < 4; j++) {
        int n = n4 + j;
        Tt[n*128 + (((k >> 3) ^ (n & 15)) << 3) + (k & 7)] = f2bf(vv[j]);
      }
    }
    __syncthreads();
    short* dst = WT + (size_t)id * 16384;
    #pragma unroll 2
    for (int i = tid; i < 2048; i += 256)
      *(bf16x8*)&dst[i*8] = *(bf16x8*)&Tt[i*8];
  } else {
    const int xb = id - 24;                       // 64 tiles
    const float* xs = x + (size_t)xb * 16384;
    short* dst = xbf + (size_t)xb * 16384;
    #pragma unroll 4
    for (int i = tid; i < 4096; i += 256) {
      float4 v = ((const float4*)xs)[i];
      int row = i >> 5, c = (i & 31) >> 1, half = i & 1;
      short4 p;
      p.x = f2bf(v.x); p.y = f2bf(v.y); p.z = f2bf(v.z); p.w = f2bf(v.w);
      *(short4*)&dst[(row*16 + (c ^ (row & 15)))*8 + half*4] = p;
    }
  }
}

// ---------------------------------------------------------------------------
// Kernel 1: QKV GEMM, fully DMA-staged. grid (64 m, 24 n=wsel*8+head).
// Epilogue: LDS image transpose + linear 32KB b128 copy-out. Q row-major
// (scaled), K/V pre-swizzled 16KB tiles (attn DMA-stageable).
// ---------------------------------------------------------------------------
__global__ __launch_bounds__(256, 2) void qkv_proj(
    const short* __restrict__ xbf, const short* __restrict__ WT,
    short* __restrict__ Qw, short* __restrict__ Kw, short* __restrict__ Vw)
{
  __shared__ __align__(16) short As[16384];
  __shared__ __align__(16) short Bs[16384];
  const int tid = threadIdx.x;
  const int w = tid >> 6, lane = tid & 63, quad = lane >> 4, l16 = lane & 15;
  const int m0 = blockIdx.x * 128;

  {
    const short* asrc = xbf + (size_t)blockIdx.x * 16384;
    const short* bsrc = WT + (size_t)blockIdx.y * 16384;
    const int so = w*4096 + lane*8;
    #pragma unroll
    for (int cc = 0; cc < 8; cc++) {
      gld16(asrc + so + cc*512, &As[w*4096 + cc*512]);
      gld16(bsrc + so + cc*512, &Bs[w*4096 + cc*512]);
    }
  }
  __syncthreads();

  const int wm = (w & 1) * 64, wn = (w >> 1) * 64;
  f32x4 acc[4][4];
  #pragma unroll
  for (int a = 0; a < 4; a++)
    #pragma unroll
    for (int b = 0; b < 4; b++) acc[a][b] = (f32x4){0.f, 0.f, 0.f, 0.f};

  #pragma unroll
  for (int kk = 0; kk < 4; kk++) {
    const int swz = ((kk*4 + quad) ^ l16) << 3;
    bf16x8 af[4], bfv[4];
    #pragma unroll
    for (int mi = 0; mi < 4; mi++) af[mi]  = *(bf16x8*)&As[(wm + mi*16 + l16)*128 + swz];
    #pragma unroll
    for (int ni = 0; ni < 4; ni++) bfv[ni] = *(bf16x8*)&Bs[(wn + ni*16 + l16)*128 + swz];
    #pragma unroll
    for (int mi = 0; mi < 4; mi++)
      #pragma unroll
      for (int ni = 0; ni < 4; ni++)
        acc[mi][ni] = __builtin_amdgcn_mfma_f32_16x16x32_bf16(af[mi], bfv[ni], acc[mi][ni], 0, 0, 0);
  }

  __syncthreads();     // all MFMA reads of As/Bs done; reuse As as image
  const int wsel = (int)blockIdx.y >> 3;
  #pragma unroll
  for (int mi = 0; mi < 4; mi++) {
    #pragma unroll
    for (int ni = 0; ni < 4; ni++) {
      const int t0l = wm + mi*16 + quad*4;        // local t rows t0l..t0l+3
      const int d   = wn + ni*16 + l16;           // local d (full head dim)
      if (wsel == 0) {
        #pragma unroll
        for (int r = 0; r < 4; r++)
          As[(t0l + r)*128 + d] = f2bf(acc[mi][ni][r] * QSCALE);
      } else if (wsel == 1) {
        const int c = d >> 3;
        #pragma unroll
        for (int r = 0; r < 4; r++) {
          const int tl = (t0l + r) & 63, tile = (t0l + r) >> 6;
          As[tile*8192 + tl*128 + ((c ^ (tl & 15)) << 3) + (d & 7)] =
              f2bf(acc[mi][ni][r]);
        }
      } else {
        #pragma unroll
        for (int r = 0; r < 4; r++) {
          const int tl = (t0l + r) & 63, tile = (t0l + r) >> 6;
          As[tile*8192 + d*64 + (((tl >> 3) ^ (d & 7)) << 3) + (tl & 7)] =
              f2bf(acc[mi][ni][r] * VSCALE);
        }
      }
    }
  }
  __syncthreads();

  const int h = (int)blockIdx.y & 7;
  const int b = m0 >> 11, t0 = m0 & 2047;
  short* base = ((wsel == 0) ? Qw : (wsel == 1) ? Kw : Vw)
              + (size_t)(b*H_ + h)*262144 + (size_t)t0*128;
  #pragma unroll 2
  for (int i = tid; i < 2048; i += 256)
    *(bf16x8*)&base[i*8] = *(bf16x8*)&As[i*8];
}

// ---------------------------------------------------------------------------
// Kernel 2: causal flash attention, double-buffered DMA pipeline, ONE barrier
// per iteration. grid 512 (2 blocks/CU, LDS 72KB). Each block: two q-tiles
// sequentially (pid, 31-pid) -> exactly 34 iterations per block, zero tail.
// ---------------------------------------------------------------------------
__global__ __launch_bounds__(256, 2) void attn_kernel(
    const short* __restrict__ Qw, const short* __restrict__ Kw,
    const short* __restrict__ Vw, short* __restrict__ attnw)
{
  __shared__ __align__(16) short Ks[2][8192];
  __shared__ __align__(16) short Vs[2][8192];
  __shared__ __align__(16) short Ps[4096];

  const int tid = threadIdx.x;
  const int id = (int)blockIdx.x;                 // 512 blocks
  const int xcd = id & 7;
  const int u   = (id >> 3) & 3;
  const int pid = id >> 5;                        // 0..15
  const int bh = xcd | (u << 3);
  const int b = bh >> 3, h = bh & 7;
  const int w = tid >> 6, lane = tid & 63, quad = lane >> 4, l16 = lane & 15;

  const short* Qp = Qw + (size_t)bh * T_ * D_;
  const short* Kp = Kw + (size_t)bh * T_ * D_;    // 32 pre-swizzled 16KB tiles
  const short* Vp = Vw + (size_t)bh * D_ * T_;
  short* Pw = &Ps[w*1024];
  const int so = w*2048 + lane*8;

  #pragma unroll 1
  for (int ph = 0; ph < 2; ph++) {
    const int qi = ph ? (31 - pid) : pid;
    const int rowQ = qi*64 + w*16;

    bf16x8 qa[4];
    #pragma unroll
    for (int kk = 0; kk < 4; kk++)
      qa[kk] = *(const bf16x8*)(Qp + (size_t)(rowQ + l16)*D_ + kk*32 + quad*8);

    f32x4 o[8];
    #pragma unroll
    for (int e = 0; e < 8; e++) o[e] = (f32x4){0,0,0,0};
    float l[4] = {0,0,0,0};

    __syncthreads();                              // prev phase fully done
    {                                             // prologue: tile 0 -> buf 0
      const short* kt = Kp;
      const short* vt = Vp;
      #pragma unroll
      for (int cc = 0; cc < 4; cc++) {
        gld16(kt + so + cc*512, &Ks[0][w*2048 + cc*512]);
        gld16(vt + so + cc*512, &Vs[0][w*2048 + cc*512]);
      }
    }
    int buf = 0;

    for (int it = 0; it <= qi; ++it) {
      __syncthreads();                            // publish buf (vmcnt drain)
      if (it < qi) {                              // prefetch next into buf^1
        const short* kt = Kp + ((size_t)(it+1) << 13);
        const short* vt = Vp + ((size_t)(it+1) << 13);
        #pragma unroll
        for (int cc = 0; cc < 4; cc++) {
          gld16(kt + so + cc*512, &Ks[buf^1][w*2048 + cc*512]);
          gld16(vt + so + cc*512, &Vs[buf^1][w*2048 + cc*512]);
        }
      }
      const short* ks = &Ks[buf][0];
      const short* vs = &Vs[buf][0];

      f32x4 s[4];
      #pragma unroll
      for (int nj = 0; nj < 4; nj++) s[nj] = (f32x4){0,0,0,0};
      #pragma unroll
      for (int kk = 0; kk < 4; kk++) {
        const int swz = ((kk*4 + quad) ^ l16) << 3;
        #pragma unroll
        for (int nj = 0; nj < 4; nj++) {
          bf16x8 kb = *(const bf16x8*)&ks[(nj*16 + l16)*128 + swz];
          s[nj] = __builtin_amdgcn_mfma_f32_16x16x32_bf16(qa[kk], kb, s[nj], 0, 0, 0);
        }
      }

      if (it < qi) {                              // unmasked tile
        #pragma unroll
        for (int nj = 0; nj < 4; nj++) {
          #pragma unroll
          for (int r = 0; r < 4; r++) {
            float p = EXP2F(s[nj][r]);
            l[r] += p;
            const int row = quad*4 + r, col = nj*16 + l16;
            Pw[row*64 + (((col >> 3) ^ (row & 7)) << 3) + (col & 7)] = f2bf(p);
          }
        }
      } else {                                    // diagonal tile: mask
        const int s0 = it * 64;
        #pragma unroll
        for (int nj = 0; nj < 4; nj++) {
          const int key = s0 + nj*16 + l16;
          #pragma unroll
          for (int r = 0; r < 4; r++) {
            float p = (key > rowQ + quad*4 + r) ? 0.f : EXP2F(s[nj][r]);
            l[r] += p;
            const int row = quad*4 + r, col = nj*16 + l16;
            Pw[row*64 + (((col >> 3) ^ (row & 7)) << 3) + (col & 7)] = f2bf(p);
          }
        }
      }

      #pragma unroll
      for (int kk2 = 0; kk2 < 2; kk2++) {
        const int swz = ((kk2*4 + quad) ^ (l16 & 7)) << 3;
        bf16x8 pa = *(bf16x8*)&Pw[l16*64 + swz];
        #pragma unroll
        for (int e = 0; e < 8; e++) {
          bf16x8 vb = *(const bf16x8*)&vs[(e*16 + l16)*64 + swz];
          o[e] = __builtin_amdgcn_mfma_f32_16x16x32_bf16(pa, vb, o[e], 0, 0, 0);
        }
      }
      buf ^= 1;
    }

    // epilogue: l-reduce, store into attnw TILE image (32rows x 128, swizzled)
    #pragma unroll
    for (int r = 0; r < 4; r++) {
      float t = l[r];
      t += __shfl_xor(t, 1); t += __shfl_xor(t, 2);
      t += __shfl_xor(t, 4); t += __shfl_xor(t, 8);
      l[r] = 1.0f / t;
    }
    const size_t tb = ((size_t)((b*2048 + rowQ) >> 5) * 8 + h) * 4096;
    const int row0 = rowQ & 31;                   // 0 or 16
    #pragma unroll
    for (int e = 0; e < 8; e++) {
      const int c = e*2 + (l16 >> 3);
      #pragma unroll
      for (int r = 0; r < 4; r++) {
        const int row = row0 + quad*4 + r;
        attnw[tb + row*128 + ((c ^ (row & 15)) << 3) + (l16 & 7)] =
            f2bf(o[e][r] * l[r]);
      }
    }
  }
}

// ---------------------------------------------------------------------------
// Kernel 3: Wu(1024x128 f32) -> WuT tile images (8 tiles of 128n x 128k,
// swizzled). grid 8, into dead Kw. Runs after attn.
// ---------------------------------------------------------------------------
__global__ __launch_bounds__(256) void wu_prep(
    const float* __restrict__ Wu, short* __restrict__ WuT)
{
  __shared__ __align__(16) short Tt[128*128];
  const int tid = threadIdx.x;
  const int kc = blockIdx.x;
  #pragma unroll 4
  for (int i = tid; i < 4096; i += 256) {
    int kl = i >> 5, n4 = (i & 31) << 2;
    float4 v = *(const float4*)&Wu[(size_t)(kc*128 + kl) * D_ + n4];
    float vv[4] = {v.x, v.y, v.z, v.w};
    #pragma unroll
    for (int j = 0; j < 4; j++) {
      int n = n4 + j;
      Tt[n*128 + (((kl >> 3) ^ (n & 15)) << 3) + (kl & 7)] = f2bf(vv[j]);
    }
  }
  __syncthreads();
  short* dst = WuT + (size_t)kc * 16384;
  #pragma unroll 2
  for (int i = tid; i < 2048; i += 256)
    *(bf16x8*)&dst[i*8] = *(bf16x8*)&Tt[i*8];
}

// ---------------------------------------------------------------------------
// Kernel 4: out = attn @ Wu + bu -> fp32. Fully DMA-staged, double-buffered
// over the 8 k-chunks, fused bias. grid 512 (m-tile 16), 2 blocks/CU.
// ---------------------------------------------------------------------------
__global__ __launch_bounds__(256, 2) void out_proj(
    const short* __restrict__ attnw, const short* __restrict__ WuT,
    const float* __restrict__ bu, float* __restrict__ out)
{
  __shared__ __align__(16) short As2[2][2048];
  __shared__ __align__(16) short Bs2[2][16384];
  const int tid = threadIdx.x;
  const int w = tid >> 6, lane = tid & 63, quad = lane >> 4, l16 = lane & 15;
  const int m0 = (int)blockIdx.x * 16;
  const int mtile32 = m0 >> 5, half = (m0 >> 4) & 1;

  f32x4 o2[2];
  o2[0] = (f32x4){0,0,0,0}; o2[1] = (f32x4){0,0,0,0};

  {                                               // prologue kc=0 -> buf0
    const short* ab = attnw + (size_t)(mtile32*8 + 0)*4096 + half*2048;
    const short* bb = WuT;
    gld16(ab + w*512 + lane*8, &As2[0][w*512]);
    #pragma unroll
    for (int cc = 0; cc < 8; cc++)
      gld16(bb + w*4096 + cc*512 + lane*8, &Bs2[0][w*4096 + cc*512]);
  }
  int buf = 0;

  for (int kc = 0; kc < 8; kc++) {
    __syncthreads();
    if (kc < 7) {
      const short* ab = attnw + (size_t)(mtile32*8 + kc + 1)*4096 + half*2048;
      const short* bb = WuT + (size_t)(kc + 1)*16384;
      gld16(ab + w*512 + lane*8, &As2[buf^1][w*512]);
      #pragma unroll
      for (int cc = 0; cc < 8; cc++)
        gld16(bb + w*4096 + cc*512 + lane*8, &Bs2[buf^1][w*4096 + cc*512]);
    }
    const short* as = &As2[buf][0];
    const short* bs = &Bs2[buf][0];
    #pragma unroll
    for (int kk = 0; kk < 4; kk++) {
      const int swz = ((kk*4 + quad) ^ l16) << 3;
      bf16x8 a = *(const bf16x8*)&as[l16*128 + swz];
      #pragma unroll
      for (int e = 0; e < 2; e++) {
        bf16x8 bfr = *(const bf16x8*)&bs[((w*2 + e)*16 + l16)*128 + swz];
        o2[e] = __builtin_amdgcn_mfma_f32_16x16x32_bf16(a, bfr, o2[e], 0, 0, 0);
      }
    }
    buf ^= 1;
  }

  #pragma unroll
  for (int e = 0; e < 2; e++) {
    const int n = (w*2 + e)*16 + l16;
    const float bias = bu[n];
    #pragma unroll
    for (int r = 0; r < 4; r++) {
      const int m = m0 + quad*4 + r;
      out[(size_t)m*D_ + n] = o2[e][r] + bias;
    }
  }
}

extern "C" void kernel_launch(void* const* d_in, const int* in_sizes, int n_in,
                              void* d_out, int out_size, void* d_ws, size_t ws_size,
                              hipStream_t stream) {
  (void)in_sizes; (void)n_in; (void)out_size; (void)ws_size;
  const float* x  = (const float*)d_in[0];
  const float* Wq = (const float*)d_in[1];
  const float* Wk = (const float*)d_in[2];
  const float* Wv = (const float*)d_in[3];
  const float* Wu = (const float*)d_in[4];
  const float* bu = (const float*)d_in[5];
  float* out = (float*)d_out;

  const size_t headElems = (size_t)B_ * H_ * T_ * D_;   // 8,388,608
  short* Qw    = (short*)d_ws;
  short* Kw    = Qw + headElems;
  short* Vw    = Kw + headElems;
  short* attnw = Vw + headElems;                        // 16 MB (tiled images)
  short* xbf = attnw;                                   // prep outputs live in
  short* WT  = attnw + 1048576;                         // not-yet-written attnw
  short* WuT = Kw;                                      // Kw dead after attn

  prep<<<dim3(88), 256, 0, stream>>>(x, Wq, Wk, Wv, xbf, WT);
  qkv_proj<<<dim3(64, 24), 256, 0, stream>>>(xbf, WT, Qw, Kw, Vw);
  attn_kernel<<<dim3(512), 256, 0, stream>>>(Qw, Kw, Vw, attnw);
  wu_prep<<<dim3(8), 256, 0, stream>>>(Wu, WuT);
  out_proj<<<dim3(512), 256, 0, stream>>>(attnw, WuT, bu, out);
}